// Round 4
// baseline (55856.329 us; speedup 1.0000x reference)
//
#include <hip/hip_runtime.h>

// ResLSTM: T=512, B=128, IN=H=1024, L=4.
// R4: ONE persistent kernel (256 WGs = 1/CU, all co-resident), superstep loop
// in-kernel with a device-scope software grid barrier (threadfence + atomic
// counter) instead of 515 kernel launches — kills per-dispatch L2-flush/ramp
// (~50us/launch observed constant across R1-R3). Stage rotation deepened to 4.

#define TT 512
#define BB 128
#define IN_D 1024
#define HH 1024
#define LL 4
#define G3 3072
#define NSUPER (TT + LL - 1)
#define KC 64
#define NCHUNK 48
#define SB_TILE 2048
#define SB_BUF 8192
#define NBUF 4
#define SLOT (BB * HH)
#define SLOT_ALL (LL * SLOT)
#define NWG 256

typedef __attribute__((ext_vector_type(8))) __bf16 bf16x8;
typedef __attribute__((ext_vector_type(4))) __bf16 bf16x4;
typedef __attribute__((ext_vector_type(4))) float f32x4;

typedef __attribute__((address_space(3))) void lds_void;
typedef const __attribute__((address_space(1))) void gmem_void;

__device__ __forceinline__ void gload_lds16(const void* g, void* l) {
    __builtin_amdgcn_global_load_lds((gmem_void*)g, (lds_void*)l, 16, 0, 0);
}

__device__ __forceinline__ f32x4 mfma16(bf16x8 a, bf16x8 b, f32x4 c) {
    return __builtin_amdgcn_mfma_f32_16x16x32_bf16(a, b, c, 0, 0, 0);
}

__device__ __forceinline__ bf16x8 ldb(const __bf16* p, int k) {
    return *reinterpret_cast<const bf16x8*>(p + k);
}

__device__ __forceinline__ bf16x8 load_a(const float* p, int k) {
    float4 a0 = *reinterpret_cast<const float4*>(p + k);
    float4 a1 = *reinterpret_cast<const float4*>(p + k + 4);
    bf16x8 r;
    r[0] = (__bf16)a0.x; r[1] = (__bf16)a0.y; r[2] = (__bf16)a0.z; r[3] = (__bf16)a0.w;
    r[4] = (__bf16)a1.x; r[5] = (__bf16)a1.y; r[6] = (__bf16)a1.z; r[7] = (__bf16)a1.w;
    return r;
}

__device__ __forceinline__ float sigm(float v) { return 1.f / (1.f + __expf(-v)); }
__device__ __forceinline__ float tanh_fast(float v) { return 1.f - 2.f / (1.f + __expf(2.f * v)); }

// ---- fused gates weight: Wg[j][n][k], k<1024:Wii, k<2048:Wih, else:Wic ----
__global__ void k_conv_gates(const float* __restrict__ Wii,
                             const float* __restrict__ Wic,
                             const float* __restrict__ Wih,
                             __bf16* __restrict__ Wg) {
    const unsigned total = (unsigned)LL * G3 * G3;
    const unsigned stride = gridDim.x * blockDim.x * 4u;
    for (unsigned idx = (blockIdx.x * blockDim.x + threadIdx.x) * 4u; idx < total; idx += stride) {
        unsigned row = idx / G3;
        int k = (int)(idx - row * G3);
        const float* src; int ks;
        if (k < 1024)      { src = Wii; ks = k; }
        else if (k < 2048) { src = Wih; ks = k - 1024; }
        else               { src = Wic; ks = k - 2048; }
        float4 v = *reinterpret_cast<const float4*>(src + (size_t)row * 1024 + ks);
        bf16x4 o;
        o[0] = (__bf16)v.x; o[1] = (__bf16)v.y; o[2] = (__bf16)v.z; o[3] = (__bf16)v.w;
        *reinterpret_cast<bf16x4*>(Wg + idx) = o;
    }
}

__global__ void k_conv_plain(const float* __restrict__ s, __bf16* __restrict__ d, unsigned total) {
    const unsigned stride = gridDim.x * blockDim.x * 4u;
    for (unsigned idx = (blockIdx.x * blockDim.x + threadIdx.x) * 4u; idx < total; idx += stride) {
        float4 v = *reinterpret_cast<const float4*>(s + idx);
        bf16x4 o;
        o[0] = (__bf16)v.x; o[1] = (__bf16)v.y; o[2] = (__bf16)v.z; o[3] = (__bf16)v.w;
        *reinterpret_cast<bf16x4*>(d + idx) = o;
    }
}

__global__ void k_bias(const float* __restrict__ bii, const float* __restrict__ bic,
                       const float* __restrict__ bih, const float* __restrict__ bhh,
                       float* __restrict__ bsum) {
    int i = blockIdx.x * blockDim.x + threadIdx.x;
    int j = i >> 12, n = i & 4095;
    if (j >= LL) return;
    if (n < G3) bsum[j * 4096 + n] = bii[j * G3 + n] + bih[j * G3 + n] + bic[j * G3 + n];
    else        bsum[j * 4096 + n] = bhh[j * HH + (n - G3)];
}

// hidden [2L,B,H] -> parity-1 slots ("t = -1")
__global__ void k_init(const float* __restrict__ hidden,
                       float* __restrict__ cbufF, __bf16* __restrict__ hb, __bf16* __restrict__ cb) {
    const unsigned stride = gridDim.x * blockDim.x;
    for (unsigned i = blockIdx.x * blockDim.x + threadIdx.x; i < SLOT_ALL; i += stride) {
        float hv = hidden[i];
        float cv = hidden[SLOT_ALL + i];
        hb[SLOT_ALL + i] = (__bf16)hv;
        cb[SLOT_ALL + i] = (__bf16)cv;
        cbufF[SLOT_ALL + i] = cv;
    }
}

__global__ void k_final(const float* __restrict__ hfin, const float* __restrict__ cbufF,
                        float* __restrict__ out_tail) {
    const unsigned stride = gridDim.x * blockDim.x;
    for (unsigned i = blockIdx.x * blockDim.x + threadIdx.x; i < SLOT_ALL; i += stride) {
        out_tail[i] = hfin[i];
        out_tail[SLOT_ALL + i] = cbufF[SLOT_ALL + i];
    }
}

// Persistent kernel: grid (64,4) x 512. WG identity: n0 = blockIdx.x*16, layer j = blockIdx.y.
// Superstep s: layer j computes t = s - j (if valid), then all 256 WGs grid-barrier.
__global__ __launch_bounds__(512, 2) void k_persist(
    const float* __restrict__ x,
    const __bf16* __restrict__ Wg,
    const __bf16* __restrict__ Whh,
    const __bf16* __restrict__ Wir,
    const float* __restrict__ bsum,
    float* __restrict__ cbufF,
    __bf16* __restrict__ hb,
    __bf16* __restrict__ cb,
    float* __restrict__ hfin,
    float* __restrict__ dout,
    unsigned* __restrict__ bar)
{
    __shared__ __align__(16) char smem[NBUF * SB_BUF];   // 32 KiB

    const int j = blockIdx.y;
    const int tid  = threadIdx.x;
    const int lane = tid & 63;
    const int wave = tid >> 6;
    const int lrow = lane & 15;
    const int kgrp = lane >> 4;
    const int n0 = blockIdx.x * 16;
    const int m0 = wave * 16;

    // staging role (per wave: one 16-row x 64k tile-half => one gload_lds16/chunk)
    const int st_tile = wave >> 1;
    const int st_half = wave & 1;
    const int st_r = st_half * 8 + (lane >> 3);
    const int st_s = lane & 7;
    const int st_k8 = ((st_s ^ (st_r & 7)) << 3);
    const __bf16* Wgj = Wg + (size_t)j * G3 * G3;
    const __bf16* st_g  = Wgj + (size_t)(st_tile * 1024 + n0 + st_r) * G3 + st_k8;
    const __bf16* st_wr = Wir + (size_t)j * HH * IN_D + (size_t)(n0 + st_r) * IN_D + st_k8;
    const __bf16* st_wc = Whh + (size_t)j * HH * HH + (size_t)(n0 + st_r) * HH + st_k8;
    char* st_dst = smem + st_tile * SB_TILE + st_half * 1024;

    // compute-side lane constants
    const int dsrow = lrow << 7;
    const int x7 = lrow & 7;
    const int so0 = ((kgrp ^ x7) << 4);
    const int so1 = (((4 | kgrp) ^ x7) << 4);
    const int aoff = (m0 + lrow) * HH + (kgrp << 3);
    const int col = n0 + lrow;

    const float b_i = bsum[j * 4096 + col];
    const float b_f = bsum[j * 4096 + HH + col];
    const float b_o = bsum[j * 4096 + 2 * HH + col];
    const float b_c = bsum[j * 4096 + G3 + col];

    for (int s = 0; s < NSUPER; ++s) {
        const int t = s - j;
        if (t >= 0 && t < TT) {
            const int p = t & 1, pp = p ^ 1;
            const float*  csrcF = cbufF + (size_t)pp * SLOT_ALL + (size_t)j * SLOT;
            float*        cdstF = cbufF + (size_t)p  * SLOT_ALL + (size_t)j * SLOT;
            const __bf16* aH = hb + (size_t)pp * SLOT_ALL + (size_t)j * SLOT + aoff;
            const __bf16* aC = cb + (size_t)pp * SLOT_ALL + (size_t)j * SLOT + aoff;
            const __bf16* aO = hb + (size_t)p * SLOT_ALL + (size_t)(j - 1) * SLOT + aoff;  // j>0
            const float*  aX = x + (size_t)t * SLOT + aoff;                                // j==0
            __bf16* hdstB = hb + (size_t)p * SLOT_ALL + (size_t)j * SLOT;
            __bf16* cdstB = cb + (size_t)p * SLOT_ALL + (size_t)j * SLOT;

            auto stage = [&](int c) {
                if (c >= NCHUNK) return;
                char* dst = st_dst + (c % NBUF) * SB_BUF;
                if (st_tile < 3) {
                    gload_lds16(st_g + (size_t)c * KC, dst);
                } else {
                    const int r = c >> 4, kb = (c & 15) << 6;
                    if (r == 0)      gload_lds16(st_wr + kb, dst);
                    else if (r == 1) gload_lds16(st_wc + kb, dst);
                }
            };
            auto loadA = [&](int c, bf16x8& r0, bf16x8& r1) {
                const int rg = c >> 4, kt = (c & 15) << 6;
                if (rg == 0) {
                    if (j == 0) { r0 = load_a(aX, kt); r1 = load_a(aX, kt + 32); }
                    else        { r0 = ldb(aO, kt);    r1 = ldb(aO, kt + 32); }
                } else if (rg == 1) { r0 = ldb(aH, kt); r1 = ldb(aH, kt + 32); }
                else                { r0 = ldb(aC, kt); r1 = ldb(aC, kt + 32); }
            };

            f32x4 vi = {0,0,0,0}, vf = {0,0,0,0}, vo = {0,0,0,0}, vc = {0,0,0,0}, vr = {0,0,0,0};
            bf16x8 a0, a1, na0, na1;

            stage(0); stage(1); stage(2);
            loadA(0, a0, a1);
            asm volatile("s_waitcnt vmcnt(4)" ::: "memory");
            __builtin_amdgcn_s_barrier();

            for (int c = 0; c < NCHUNK; ++c) {
                const int rg = c >> 4;
                char* bs = smem + (c % NBUF) * SB_BUF;

                if (c + 1 < NCHUNK) loadA(c + 1, na0, na1);
                stage(c + 3);

                bf16x8 b;
                b = *(const bf16x8*)(bs + 0 * SB_TILE + dsrow + so0); vi = mfma16(a0, b, vi);
                b = *(const bf16x8*)(bs + 1 * SB_TILE + dsrow + so0); vf = mfma16(a0, b, vf);
                b = *(const bf16x8*)(bs + 2 * SB_TILE + dsrow + so0); vo = mfma16(a0, b, vo);
                if (rg == 0)      { b = *(const bf16x8*)(bs + 3 * SB_TILE + dsrow + so0); vr = mfma16(a0, b, vr); }
                else if (rg == 1) { b = *(const bf16x8*)(bs + 3 * SB_TILE + dsrow + so0); vc = mfma16(a0, b, vc); }
                b = *(const bf16x8*)(bs + 0 * SB_TILE + dsrow + so1); vi = mfma16(a1, b, vi);
                b = *(const bf16x8*)(bs + 1 * SB_TILE + dsrow + so1); vf = mfma16(a1, b, vf);
                b = *(const bf16x8*)(bs + 2 * SB_TILE + dsrow + so1); vo = mfma16(a1, b, vo);
                if (rg == 0)      { b = *(const bf16x8*)(bs + 3 * SB_TILE + dsrow + so1); vr = mfma16(a1, b, vr); }
                else if (rg == 1) { b = *(const bf16x8*)(bs + 3 * SB_TILE + dsrow + so1); vc = mfma16(a1, b, vc); }

                a0 = na0; a1 = na1;
                asm volatile("s_waitcnt vmcnt(4)" ::: "memory");
                __builtin_amdgcn_s_barrier();
            }

            // elementwise epilogue
            #pragma unroll
            for (int r = 0; r < 4; ++r) {
                const int m = m0 + kgrp * 4 + r;
                const size_t o = (size_t)m * HH + col;
                float iv = vi[r] + b_i;
                float fv = vf[r] + b_f;
                float ov = vo[r] + b_o;
                float cg = tanh_fast(vc[r] + b_c);
                float cold = csrcF[o];
                float cy = sigm(fv) * cold + sigm(iv) * cg;
                float hy = sigm(ov) * (tanh_fast(cy) + vr[r]);
                cdstF[o] = cy;
                cdstB[o] = (__bf16)cy;
                hdstB[o] = (__bf16)hy;
                if (t == TT - 1) hfin[(size_t)j * SLOT + o] = hy;
                if (j == LL - 1) dout[(size_t)t * SLOT + o] = hy;
            }
        }

        // ---- device-scope grid barrier (all 256 WGs, every superstep) ----
        __syncthreads();                       // drain all waves' stores (emits vmcnt(0) before s_barrier)
        if (tid == 0) {
            __threadfence();                   // agent release (L2 writeback)
            __hip_atomic_fetch_add(bar, 1u, __ATOMIC_RELAXED, __HIP_MEMORY_SCOPE_AGENT);
            const unsigned tgt = (unsigned)(s + 1) * NWG;
            while (__hip_atomic_load(bar, __ATOMIC_ACQUIRE, __HIP_MEMORY_SCOPE_AGENT) < tgt)
                __builtin_amdgcn_s_sleep(2);
            __threadfence();                   // agent acquire (invalidate)
        }
        __syncthreads();
    }
}

extern "C" void kernel_launch(void* const* d_in, const int* in_sizes, int n_in,
                              void* d_out, int out_size, void* d_ws, size_t ws_size,
                              hipStream_t stream) {
    const float* x      = (const float*)d_in[0];
    const float* hidden = (const float*)d_in[1];
    const float* Wii    = (const float*)d_in[2];
    const float* Wic    = (const float*)d_in[3];
    const float* Wih    = (const float*)d_in[4];
    const float* bii    = (const float*)d_in[5];
    const float* bic    = (const float*)d_in[6];
    const float* bih    = (const float*)d_in[7];
    const float* Whh    = (const float*)d_in[8];
    const float* bhh    = (const float*)d_in[9];
    const float* Wir    = (const float*)d_in[10];
    float* out = (float*)d_out;

    // ws layout (bytes):
    //   Wg     @ 0          75,497,472
    //   Whh_b  @ 75497472    8,388,608
    //   Wir_b  @ 83886080    8,388,608
    //   cbufF  @ 92274688    4,194,304
    //   bsum   @ 96468992       65,536
    //   hb     @ 96534528    2,097,152
    //   cb     @ 98631680    2,097,152
    //   hfin   @ 100728832   2,097,152
    //   bar    @ 102825984          64
    char* ws = (char*)d_ws;
    __bf16* Wg    = (__bf16*)(ws);
    __bf16* Whh_b = (__bf16*)(ws + 75497472);
    __bf16* Wir_b = (__bf16*)(ws + 83886080);
    float*  cbufF = (float*)(ws + 92274688);
    float*  bsum  = (float*)(ws + 96468992);
    __bf16* hb    = (__bf16*)(ws + 96534528);
    __bf16* cb    = (__bf16*)(ws + 98631680);
    float*  hfin  = (float*)(ws + 100728832);
    unsigned* bar = (unsigned*)(ws + 102825984);

    hipMemsetAsync(bar, 0, 64, stream);
    k_conv_gates<<<4096, 256, 0, stream>>>(Wii, Wic, Wih, Wg);
    k_conv_plain<<<2048, 256, 0, stream>>>(Whh, Whh_b, (unsigned)(LL * HH * HH));
    k_conv_plain<<<2048, 256, 0, stream>>>(Wir, Wir_b, (unsigned)(LL * HH * IN_D));
    k_bias<<<64, 256, 0, stream>>>(bii, bic, bih, bhh, bsum);
    k_init<<<1024, 256, 0, stream>>>(hidden, cbufF, hb, cb);

    dim3 grid(64, LL), block(512);
    k_persist<<<grid, block, 0, stream>>>(x, Wg, Whh_b, Wir_b, bsum,
                                          cbufF, hb, cb, hfin, out, bar);

    k_final<<<1024, 256, 0, stream>>>(hfin, cbufF, out + (size_t)TT * SLOT);
}

// Round 5
// 36179.718 us; speedup vs baseline: 1.5439x; 1.5439x over previous
//
#include <hip/hip_runtime.h>

// ResLSTM: T=512, B=128, IN=H=1024, L=4. Launch-per-superstep (515), diagonal wavefront.
// R5: A-operands staged through LDS via global_load_lds (like B), KC=32, NBUF=4 depth-3
// rotation with exact per-wave counted vmcnt -> waves keep 2-3 stage ops in flight
// continuously instead of draining to ~0 every chunk (R3/R4's latency serialization).
// Layer-0 x (f32) stays register-direct with 1-chunk prefetch.

#define TT 512
#define BB 128
#define IN_D 1024
#define HH 1024
#define LL 4
#define G3 3072
#define NSUPER (TT + LL - 1)
#define KC 32
#define NCHUNK 96            // 32 chunks per rg (rg0: A=out, rg1: A=h, rg2: A=c)
#define B_AREA 4096          // 4 groups x 16 rows x 64 B
#define A_AREA 8192          // 128 rows x 64 B
#define BUF_SZ (B_AREA + A_AREA)
#define NBUF 4
#define SLOT (BB * HH)
#define SLOT_ALL (LL * SLOT)

typedef __attribute__((ext_vector_type(8))) __bf16 bf16x8;
typedef __attribute__((ext_vector_type(4))) __bf16 bf16x4;
typedef __attribute__((ext_vector_type(4))) float f32x4;

typedef __attribute__((address_space(3))) void lds_void;
typedef const __attribute__((address_space(1))) void gmem_void;

__device__ __forceinline__ void gload_lds16(const void* g, void* l) {
    __builtin_amdgcn_global_load_lds((gmem_void*)g, (lds_void*)l, 16, 0, 0);
}

__device__ __forceinline__ f32x4 mfma16(bf16x8 a, bf16x8 b, f32x4 c) {
    return __builtin_amdgcn_mfma_f32_16x16x32_bf16(a, b, c, 0, 0, 0);
}

__device__ __forceinline__ int srow(int r) { return (r & 3) ^ ((r >> 2) & 3); }

__device__ __forceinline__ bf16x8 cvt8(float4 u, float4 v) {
    bf16x8 r;
    r[0] = (__bf16)u.x; r[1] = (__bf16)u.y; r[2] = (__bf16)u.z; r[3] = (__bf16)u.w;
    r[4] = (__bf16)v.x; r[5] = (__bf16)v.y; r[6] = (__bf16)v.z; r[7] = (__bf16)v.w;
    return r;
}

__device__ __forceinline__ float sigm(float v) { return 1.f / (1.f + __expf(-v)); }
__device__ __forceinline__ float tanh_fast(float v) { return 1.f - 2.f / (1.f + __expf(2.f * v)); }

// ---- fused gates weight: Wg[j][n][k], k<1024:Wii, k<2048:Wih, else:Wic ----
__global__ void k_conv_gates(const float* __restrict__ Wii,
                             const float* __restrict__ Wic,
                             const float* __restrict__ Wih,
                             __bf16* __restrict__ Wg) {
    const unsigned total = (unsigned)LL * G3 * G3;
    const unsigned stride = gridDim.x * blockDim.x * 4u;
    for (unsigned idx = (blockIdx.x * blockDim.x + threadIdx.x) * 4u; idx < total; idx += stride) {
        unsigned row = idx / G3;
        int k = (int)(idx - row * G3);
        const float* src; int ks;
        if (k < 1024)      { src = Wii; ks = k; }
        else if (k < 2048) { src = Wih; ks = k - 1024; }
        else               { src = Wic; ks = k - 2048; }
        float4 v = *reinterpret_cast<const float4*>(src + (size_t)row * 1024 + ks);
        bf16x4 o;
        o[0] = (__bf16)v.x; o[1] = (__bf16)v.y; o[2] = (__bf16)v.z; o[3] = (__bf16)v.w;
        *reinterpret_cast<bf16x4*>(Wg + idx) = o;
    }
}

__global__ void k_conv_plain(const float* __restrict__ s, __bf16* __restrict__ d, unsigned total) {
    const unsigned stride = gridDim.x * blockDim.x * 4u;
    for (unsigned idx = (blockIdx.x * blockDim.x + threadIdx.x) * 4u; idx < total; idx += stride) {
        float4 v = *reinterpret_cast<const float4*>(s + idx);
        bf16x4 o;
        o[0] = (__bf16)v.x; o[1] = (__bf16)v.y; o[2] = (__bf16)v.z; o[3] = (__bf16)v.w;
        *reinterpret_cast<bf16x4*>(d + idx) = o;
    }
}

__global__ void k_bias(const float* __restrict__ bii, const float* __restrict__ bic,
                       const float* __restrict__ bih, const float* __restrict__ bhh,
                       float* __restrict__ bsum) {
    int i = blockIdx.x * blockDim.x + threadIdx.x;
    int j = i >> 12, n = i & 4095;
    if (j >= LL) return;
    if (n < G3) bsum[j * 4096 + n] = bii[j * G3 + n] + bih[j * G3 + n] + bic[j * G3 + n];
    else        bsum[j * 4096 + n] = bhh[j * HH + (n - G3)];
}

// hidden [2L,B,H] -> parity-1 slots ("t = -1")
__global__ void k_init(const float* __restrict__ hidden,
                       float* __restrict__ cbufF, __bf16* __restrict__ hb, __bf16* __restrict__ cb) {
    const unsigned stride = gridDim.x * blockDim.x;
    for (unsigned i = blockIdx.x * blockDim.x + threadIdx.x; i < SLOT_ALL; i += stride) {
        float hv = hidden[i];
        float cv = hidden[SLOT_ALL + i];
        hb[SLOT_ALL + i] = (__bf16)hv;
        cb[SLOT_ALL + i] = (__bf16)cv;
        cbufF[SLOT_ALL + i] = cv;
    }
}

__global__ void k_final(const float* __restrict__ hfin, const float* __restrict__ cbufF,
                        float* __restrict__ out_tail) {
    const unsigned stride = gridDim.x * blockDim.x;
    for (unsigned i = blockIdx.x * blockDim.x + threadIdx.x; i < SLOT_ALL; i += stride) {
        out_tail[i] = hfin[i];
        out_tail[SLOT_ALL + i] = cbufF[SLOT_ALL + i];
    }
}

// superstep s: layer j = blockIdx.y computes t = s - j. grid (64,4) x 512 threads.
// WG: BM=128 x BN=16, wave w owns rows 16w. K walk: 96 chunks of KC=32.
//   rg0 (c<32):  A = layer input (x / prev-layer h), B groups {wi,wf,wo,wr}
//   rg1 (c<64):  A = h,  B groups {wi,wf,wo,wc}
//   rg2 (c<96):  A = c,  B groups {wi,wf,wo} (grp3 staged dup, unread)
// LDS per buf: B 4x[16 rows x 64B] + A [128 rows x 64B]; 16B slots XOR-swizzled by
// s(row)=(row&3)^((row>>2)&3). Staging: waves 0-3 stage B grp w (1 op), waves 4-7
// stage A rows 32(w-4)..+32 (2 ops). Exact waits: vmcnt(2) / vmcnt(4), depth-3.
__global__ __launch_bounds__(512) void k_super(
    const float* __restrict__ x,
    const __bf16* __restrict__ Wg,
    const __bf16* __restrict__ Whh,
    const __bf16* __restrict__ Wir,
    const float* __restrict__ bsum,
    float* __restrict__ cbufF,
    __bf16* __restrict__ hb,
    __bf16* __restrict__ cb,
    float* __restrict__ hfin,
    float* __restrict__ dout,
    int s)
{
    const int j = blockIdx.y;
    const int t = s - j;
    if (t < 0 || t >= TT) return;

    __shared__ __align__(16) char smem[NBUF * BUF_SZ];   // 48 KiB

    const int p = t & 1, pp = p ^ 1;
    const float*  csrcF = cbufF + (size_t)pp * SLOT_ALL + (size_t)j * SLOT;
    float*        cdstF = cbufF + (size_t)p  * SLOT_ALL + (size_t)j * SLOT;
    const __bf16* panH = hb + (size_t)pp * SLOT_ALL + (size_t)j * SLOT;          // rg1 A
    const __bf16* panC = cb + (size_t)pp * SLOT_ALL + (size_t)j * SLOT;          // rg2 A
    const __bf16* panO = hb + (size_t)p * SLOT_ALL + (size_t)(j - 1) * SLOT;     // rg0 A (j>0)
    __bf16* hdstB = hb + (size_t)p * SLOT_ALL + (size_t)j * SLOT;
    __bf16* cdstB = cb + (size_t)p * SLOT_ALL + (size_t)j * SLOT;

    const int tid  = threadIdx.x;
    const int lane = tid & 63;
    const int wave = tid >> 6;
    const int lrow = lane & 15;
    const int kgrp = lane >> 4;
    const int n0 = blockIdx.x * 16;
    const int m0 = wave * 16;

    // ---------- staging lane constants ----------
    // B-role (waves 0-3): group = wave; op = 16 rows x 64 B
    const int bs_row = lane >> 2;                 // 0..15 (weight row within group)
    const int bs_phys = lane & 3;                 // physical 16B slot
    const int bs_k8 = ((bs_phys ^ srow(bs_row)) << 3);  // logical k offset (elements)
    const __bf16* Wgj = Wg + (size_t)j * G3 * G3;
    const __bf16* st_g  = Wgj + (size_t)(wave * 1024 + n0 + bs_row) * G3 + bs_k8;    // waves 0-2
    const __bf16* st_wr = Wir + (size_t)j * HH * IN_D + (size_t)(n0 + bs_row) * IN_D + bs_k8;
    const __bf16* st_wc = Whh + (size_t)j * HH * HH + (size_t)(n0 + bs_row) * HH + bs_k8;
    const int bs_dst = wave * 1024 + lane * 16;   // within B area

    // A-role (waves 4-7): 2 ops, rows (wave-4)*32 + {0..15, 16..31}
    const int ao = (wave - 4) * 2;                // first op index (0,2,4,6)
    const int as_rowin = lane >> 2;               // row within op
    const int as_phys = lane & 3;
    const int as_k8 = ((as_phys ^ srow(as_rowin)) << 3);
    const int as_row0 = ao * 16 + as_rowin;
    const size_t paoff0 = (size_t)as_row0 * HH + as_k8;
    const size_t paoff1 = paoff0 + (size_t)16 * HH;
    const int as_dst0 = B_AREA + ao * 1024 + lane * 16;
    const int as_dst1 = as_dst0 + 1024;

    // ---------- compute lane constants ----------
    // B frag read: group g at g*1024 + lrow*64 + ((kgrp^s(lrow))<<4)
    const int bswz = ((kgrp ^ srow(lrow)) << 4);
    const int boff0 = 0 * 1024 + lrow * 64 + bswz;
    const int boff1 = 1 * 1024 + lrow * 64 + bswz;
    const int boff2 = 2 * 1024 + lrow * 64 + bswz;
    const int boff3 = 3 * 1024 + lrow * 64 + bswz;
    // A frag read: row = m0+lrow; (row&15)==lrow so same swizzle term
    const int aoff = B_AREA + (m0 + lrow) * 64 + bswz;

    const float* aX = x + (size_t)t * SLOT + (size_t)(m0 + lrow) * IN_D + kgrp * 8;

    auto stage = [&](int c) {
        if (c >= NCHUNK) return;
        const int rg = c >> 5;
        const int kk = (c & 31) << 5;
        char* buf = smem + (c & 3) * BUF_SZ;
        if (wave < 3) {
            gload_lds16(st_g + rg * 1024 + kk, buf + bs_dst);
        } else if (wave == 3) {
            if (rg == 0)      gload_lds16(st_wr + kk, buf + bs_dst);
            else              gload_lds16(st_wc + kk, buf + bs_dst);  // rg2: dup, unread
        } else {
            if (rg == 0) {
                if (j > 0) {
                    gload_lds16(panO + paoff0 + kk, buf + as_dst0);
                    gload_lds16(panO + paoff1 + kk, buf + as_dst1);
                }
            } else if (rg == 1) {
                gload_lds16(panH + paoff0 + kk, buf + as_dst0);
                gload_lds16(panH + paoff1 + kk, buf + as_dst1);
            } else {
                gload_lds16(panC + paoff0 + kk, buf + as_dst0);
                gload_lds16(panC + paoff1 + kk, buf + as_dst1);
            }
        }
    };

    f32x4 vi = {0,0,0,0}, vf = {0,0,0,0}, vo = {0,0,0,0}, vc = {0,0,0,0}, vr = {0,0,0,0};

    float4 x0, x1;
    if (j == 0) { x0 = *(const float4*)(aX); x1 = *(const float4*)(aX + 4); }

    stage(0); stage(1); stage(2);
    if (wave < 4) asm volatile("s_waitcnt vmcnt(2)" ::: "memory");
    else          asm volatile("s_waitcnt vmcnt(4)" ::: "memory");
    __builtin_amdgcn_s_barrier();

    for (int c = 0; c < NCHUNK; ++c) {
        const int rg = c >> 5;
        char* buf = smem + (c & 3) * BUF_SZ;

        bf16x8 a;
        if (j == 0 && rg == 0) {
            a = cvt8(x0, x1);
            if (c + 1 < 32) {
                const float* px = aX + ((c + 1) << 5);
                x0 = *(const float4*)(px); x1 = *(const float4*)(px + 4);
            }
        } else {
            a = *(const bf16x8*)(buf + aoff);
        }

        stage(c + 3);

        bf16x8 b;
        b = *(const bf16x8*)(buf + boff0); vi = mfma16(a, b, vi);
        b = *(const bf16x8*)(buf + boff1); vf = mfma16(a, b, vf);
        b = *(const bf16x8*)(buf + boff2); vo = mfma16(a, b, vo);
        if (rg == 0)      { b = *(const bf16x8*)(buf + boff3); vr = mfma16(a, b, vr); }
        else if (rg == 1) { b = *(const bf16x8*)(buf + boff3); vc = mfma16(a, b, vc); }

        if (wave < 4) asm volatile("s_waitcnt vmcnt(2)" ::: "memory");
        else          asm volatile("s_waitcnt vmcnt(4)" ::: "memory");
        __builtin_amdgcn_s_barrier();
    }

    // ---- elementwise epilogue ----
    const int col = n0 + lrow;
    const float b_i = bsum[j * 4096 + col];
    const float b_f = bsum[j * 4096 + HH + col];
    const float b_o = bsum[j * 4096 + 2 * HH + col];
    const float b_c = bsum[j * 4096 + G3 + col];

    #pragma unroll
    for (int r = 0; r < 4; ++r) {
        const int m = m0 + kgrp * 4 + r;
        const size_t o = (size_t)m * HH + col;
        float iv = vi[r] + b_i;
        float fv = vf[r] + b_f;
        float ov = vo[r] + b_o;
        float cg = tanh_fast(vc[r] + b_c);
        float cold = csrcF[o];
        float cy = sigm(fv) * cold + sigm(iv) * cg;
        float hy = sigm(ov) * (tanh_fast(cy) + vr[r]);
        cdstF[o] = cy;
        cdstB[o] = (__bf16)cy;
        hdstB[o] = (__bf16)hy;
        if (t == TT - 1) hfin[(size_t)j * SLOT + o] = hy;
        if (j == LL - 1) dout[(size_t)t * SLOT + o] = hy;
    }
}

extern "C" void kernel_launch(void* const* d_in, const int* in_sizes, int n_in,
                              void* d_out, int out_size, void* d_ws, size_t ws_size,
                              hipStream_t stream) {
    const float* x      = (const float*)d_in[0];
    const float* hidden = (const float*)d_in[1];
    const float* Wii    = (const float*)d_in[2];
    const float* Wic    = (const float*)d_in[3];
    const float* Wih    = (const float*)d_in[4];
    const float* bii    = (const float*)d_in[5];
    const float* bic    = (const float*)d_in[6];
    const float* bih    = (const float*)d_in[7];
    const float* Whh    = (const float*)d_in[8];
    const float* bhh    = (const float*)d_in[9];
    const float* Wir    = (const float*)d_in[10];
    float* out = (float*)d_out;

    // ws layout (bytes):
    //   Wg     @ 0          75,497,472
    //   Whh_b  @ 75497472    8,388,608
    //   Wir_b  @ 83886080    8,388,608
    //   cbufF  @ 92274688    4,194,304
    //   bsum   @ 96468992       65,536
    //   hb     @ 96534528    2,097,152
    //   cb     @ 98631680    2,097,152
    //   hfin   @ 100728832   2,097,152
    char* ws = (char*)d_ws;
    __bf16* Wg    = (__bf16*)(ws);
    __bf16* Whh_b = (__bf16*)(ws + 75497472);
    __bf16* Wir_b = (__bf16*)(ws + 83886080);
    float*  cbufF = (float*)(ws + 92274688);
    float*  bsum  = (float*)(ws + 96468992);
    __bf16* hb    = (__bf16*)(ws + 96534528);
    __bf16* cb    = (__bf16*)(ws + 98631680);
    float*  hfin  = (float*)(ws + 100728832);

    k_conv_gates<<<4096, 256, 0, stream>>>(Wii, Wic, Wih, Wg);
    k_conv_plain<<<2048, 256, 0, stream>>>(Whh, Whh_b, (unsigned)(LL * HH * HH));
    k_conv_plain<<<2048, 256, 0, stream>>>(Wir, Wir_b, (unsigned)(LL * HH * IN_D));
    k_bias<<<64, 256, 0, stream>>>(bii, bic, bih, bhh, bsum);
    k_init<<<1024, 256, 0, stream>>>(hidden, cbufF, hb, cb);

    dim3 grid(64, LL), block(512);
    for (int s = 0; s < NSUPER; ++s)
        k_super<<<grid, block, 0, stream>>>(x, Wg, Whh_b, Wir_b, bsum,
                                            cbufF, hb, cb, hfin, out, s);

    k_final<<<1024, 256, 0, stream>>>(hfin, cbufF, out + (size_t)TT * SLOT);
}